// Round 11
// baseline (144.494 us; speedup 1.0000x reference)
//
#include <hip/hip_runtime.h>
#include <math.h>

#define N_NODES 20000
#define IN_DIM  512
#define HID     128
#define HEADS   8
#define C_DIM   16
#define LAYERS  2
#define NEDGE   320000
#define NEG_SLOPE 0.2f
#define LN_EPS  1e-5f
#define CAP     64   // ELL capacity (incl. self loop); deg ~ Poisson(16)
#define SLOTS   16   // edge slots per k_gat chunk

#define PROJ_BLKS  625                         // N_NODES/32
#define EDGE_BLKS  ((NEDGE + 127) / 128)       // 2500
#define SELF_BLKS  ((N_NODES + 127) / 128)     // 157

typedef __attribute__((ext_vector_type(8))) short short8;
typedef __attribute__((ext_vector_type(4))) float f32x4;

__device__ __forceinline__ unsigned short f2bf(float f) {
    unsigned int u = __float_as_uint(f);
    u += 0x7fffu + ((u >> 16) & 1u);
    return (unsigned short)(u >> 16);
}
__device__ __forceinline__ float bf2f(unsigned short s) {
    return __uint_as_float(((unsigned int)s) << 16);
}

// ------- one-time: cnt=0; weights -> bf16 transposed [n][k] (coalesced reads) -------
__global__ __launch_bounds__(256) void k_convert(
    const float* __restrict__ W_in, const float* __restrict__ Wl, const float* __restrict__ Wr,
    unsigned short* __restrict__ WtI, unsigned short* __restrict__ Wlt, unsigned short* __restrict__ Wrt,
    int* __restrict__ cnt)
{
    int i = blockIdx.x * 256 + threadIdx.x;
    if (i < N_NODES) cnt[i] = 0;
    if (i < 65536) {                      // read W_in[k][n] coalesced, write WtI[n][k]
        int n = i & 127, k = i >> 7;
        WtI[(unsigned)n * IN_DIM + k] = f2bf(W_in[(unsigned)k * HID + n]);
    } else if (i < 98304) {               // Wlt[L][n][k]
        int r = i - 65536;
        int L = r >> 14, q = r & 16383;
        int n = q & 127, k = q >> 7;
        Wlt[L * 16384 + n * HID + k] = f2bf(Wl[L * 16384 + k * HID + n]);
    } else if (i < 131072) {              // Wrt[L][n][k]
        int r = i - 98304;
        int L = r >> 14, q = r & 16383;
        int n = q & 127, k = q >> 7;
        Wrt[L * 16384 + n * HID + k] = f2bf(Wr[L * 16384 + k * HID + n]);
    }
}

// ------- fused: input proj (blocks [0,625)) + edge build + self-loop insert -------
// proj: x-tile in LDS (1 barrier), B-fragments direct from L2-hot WtI.
__global__ __launch_bounds__(128) void k_fused0(
    const float* __restrict__ x, const unsigned short* __restrict__ WtI,
    const float* __restrict__ b, const float* __restrict__ g, const float* __restrict__ beta,
    unsigned short* __restrict__ hb,
    const int* __restrict__ ei, int* __restrict__ cnt, int* __restrict__ adj)
{
    __shared__ unsigned short xtile[32][520];   // [row][k] bf16, stride 520 (bank-floor)
    const int bid = blockIdx.x;
    const int tid = threadIdx.x;

    if (bid >= PROJ_BLKS) {
        if (bid < PROJ_BLKS + EDGE_BLKS) {
            int e = (bid - PROJ_BLKS) * 128 + tid;
            if (e < NEDGE) {
                int src = ei[e];
                int dst = ei[NEDGE + e];
                int r = atomicAdd(&cnt[dst], 1);
                if (r < CAP) adj[(unsigned)dst * CAP + r] = src;
            }
        } else {
            int i = (bid - PROJ_BLKS - EDGE_BLKS) * 128 + tid;
            if (i < N_NODES) {
                int r = atomicAdd(&cnt[i], 1);
                if (r < CAP) adj[(unsigned)i * CAP + r] = i;
            }
        }
        return;
    }

    const int wid = tid >> 6;
    const int l   = tid & 63;
    const int grp = l >> 4;
    const int ln  = l & 15;
    const int row0 = bid * 32;

    // stage full x-tile once: thread -> row tid>>2, col block (tid&3)*128
    {
        const int xrr = tid >> 2;
        const int xc0 = (tid & 3) * 128;
        const float4* ps = (const float4*)&x[(unsigned)(row0 + xrr) * IN_DIM + xc0];
#pragma unroll
        for (int q = 0; q < 16; ++q) {
            float4 va = ps[2 * q], vb = ps[2 * q + 1];
            short8 o;
            o[0] = (short)f2bf(va.x); o[1] = (short)f2bf(va.y);
            o[2] = (short)f2bf(va.z); o[3] = (short)f2bf(va.w);
            o[4] = (short)f2bf(vb.x); o[5] = (short)f2bf(vb.y);
            o[6] = (short)f2bf(vb.z); o[7] = (short)f2bf(vb.w);
            *(short8*)&xtile[xrr][xc0 + q * 8] = o;
        }
    }
    __syncthreads();

    f32x4 acc[8];
#pragma unroll
    for (int j = 0; j < 8; ++j) acc[j] = (f32x4){0.f, 0.f, 0.f, 0.f};

    for (int ks = 0; ks < 16; ++ks) {
        short8 a = *(short8*)&xtile[wid * 16 + ln][ks * 32 + grp * 8];
#pragma unroll
        for (int j = 0; j < 8; ++j) {
            short8 bf = *(const short8*)&WtI[(unsigned)(j * 16 + ln) * IN_DIM + ks * 32 + grp * 8];
            acc[j] = __builtin_amdgcn_mfma_f32_16x16x32_bf16(a, bf, acc[j], 0, 0, 0);
        }
    }

    // epilogue: +bias, LN over 128 cols, ReLU
    float s1[4] = {0, 0, 0, 0}, s2[4] = {0, 0, 0, 0};
#pragma unroll
    for (int j = 0; j < 8; ++j) {
        float bb = b[j * 16 + ln];
#pragma unroll
        for (int r = 0; r < 4; ++r) {
            float v = acc[j][r] + bb;
            acc[j][r] = v;
            s1[r] += v; s2[r] += v * v;
        }
    }
#pragma unroll
    for (int r = 0; r < 4; ++r) {
#pragma unroll
        for (int off = 8; off; off >>= 1) {
            s1[r] += __shfl_xor(s1[r], off);
            s2[r] += __shfl_xor(s2[r], off);
        }
    }
#pragma unroll
    for (int r = 0; r < 4; ++r) {
        float mu  = s1[r] * (1.f / HID);
        float var = s2[r] * (1.f / HID) - mu * mu;
        float rs  = rsqrtf(var + LN_EPS);
        int row = row0 + wid * 16 + grp * 4 + r;
#pragma unroll
        for (int j = 0; j < 8; ++j) {
            int c = j * 16 + ln;
            float o = (acc[j][r] - mu) * rs * g[c] + beta[c];
            hb[(unsigned)row * HID + c] = f2bf(fmaxf(o, 0.f));
        }
    }
}

// ------- per-layer MFMA: 4 waves = (row-half, L/R); no LDS, no barriers -------
__global__ __launch_bounds__(256) void k_xlxr(
    const unsigned short* __restrict__ hb,
    const unsigned short* __restrict__ Wlt, const unsigned short* __restrict__ Wrt,
    const float* __restrict__ bl, const float* __restrict__ br,
    unsigned short* __restrict__ xlb, unsigned short* __restrict__ xrb)
{
    const int tid = threadIdx.x;
    const int wv  = tid >> 6;          // 0..3: (wv&1)=row half, (wv>>1)=L/R
    const int l   = tid & 63;
    const int grp = l >> 4;
    const int ln  = l & 15;
    const int row0 = blockIdx.x * 32 + (wv & 1) * 16;
    const int arow = row0 + ln;

    const unsigned short* W    = (wv < 2) ? Wlt : Wrt;
    const float*          bias = (wv < 2) ? bl : br;
    unsigned short*       outp = (wv < 2) ? xlb : xrb;

    short8 a[4];
#pragma unroll
    for (int ks = 0; ks < 4; ++ks)
        a[ks] = *(const short8*)&hb[(unsigned)arow * HID + ks * 32 + grp * 8];

    f32x4 acc[8];
#pragma unroll
    for (int j = 0; j < 8; ++j) acc[j] = (f32x4){0.f, 0.f, 0.f, 0.f};
#pragma unroll
    for (int j = 0; j < 8; ++j) {
        const unsigned short* pw = &W[(unsigned)(j * 16 + ln) * HID + grp * 8];
#pragma unroll
        for (int ks = 0; ks < 4; ++ks) {
            short8 b8 = *(const short8*)&pw[ks * 32];
            acc[j] = __builtin_amdgcn_mfma_f32_16x16x32_bf16(a[ks], b8, acc[j], 0, 0, 0);
        }
    }
#pragma unroll
    for (int r = 0; r < 4; ++r) {
        int row = row0 + grp * 4 + r;
#pragma unroll
        for (int j = 0; j < 8; ++j) {
            int c = j * 16 + ln;
            outp[(unsigned)row * HID + c] = f2bf(acc[j][r] + bias[c]);
        }
    }
}

// per-slot work: convert gathered row, logit, exp, accumulate
#define PROC(xa, xb, live) do {                                             \
    float xf[16];                                                           \
    _Pragma("unroll")                                                       \
    for (int q = 0; q < 8; ++q) {                                           \
        xf[q]     = bf2f((unsigned short)(xa)[q]);                          \
        xf[8 + q] = bf2f((unsigned short)(xb)[q]);                          \
    }                                                                       \
    float ll = 0.f;                                                         \
    _Pragma("unroll")                                                       \
    for (int q = 0; q < 16; ++q) {                                          \
        float u = xf[q] + rv[q];                                            \
        u = fmaxf(u, NEG_SLOPE * u);                                        \
        ll = fmaf(av[q], u, ll);                                            \
    }                                                                       \
    float p = (live) ? __expf(ll) : 0.f;                                    \
    s_part += p;                                                            \
    _Pragma("unroll")                                                       \
    for (int q = 0; q < 16; ++q) acc[q] = fmaf(p, xf[q], acc[q]);           \
} while (0)

// ------- fused GAT layer: 2 nodes/block (independent halves), swizzled reduce -------
// half = t>>7; within half: thread (e,hh) = (tl>>3, tl&7)
__global__ __launch_bounds__(256) void k_gat(
    const unsigned short* __restrict__ xlb, const unsigned short* __restrict__ xrb,
    const int* __restrict__ adj, const int* __restrict__ cnt,
    const float* __restrict__ att, const float* __restrict__ gbias,
    const float* __restrict__ g, const float* __restrict__ beta,
    const unsigned short* __restrict__ hbin, float* __restrict__ hout,
    unsigned short* __restrict__ hbout)
{
    __shared__ int   adjs[2][CAP];
    __shared__ float lacc[2][SLOTS][132];   // row stride 33 float4s (odd) -> bank spread
    __shared__ float ls[2][SLOTS][HEADS];
    __shared__ float tmp[2][4];
    const int t    = threadIdx.x;
    const int half = t >> 7;
    const int tl   = t & 127;
    const int d    = blockIdx.x * 2 + half;
    const int e    = tl >> 3;
    const int hh   = tl & 7;
    const int cb   = hh * 16;

    const int nj = min(cnt[d], CAP);     // includes self loop (atomic insert)
    if (tl < nj) adjs[half][tl] = adj[(unsigned)d * CAP + tl];
    __syncthreads();

    float av[16], rv[16];
#pragma unroll
    for (int q = 0; q < 4; ++q) {
        float4 a4 = *(const float4*)&att[cb + q * 4];
        av[q*4+0] = a4.x; av[q*4+1] = a4.y; av[q*4+2] = a4.z; av[q*4+3] = a4.w;
    }
    {
        const short8* pr = (const short8*)&xrb[(unsigned)d * HID + cb];
        short8 r0 = pr[0], r1 = pr[1];
#pragma unroll
        for (int q = 0; q < 8; ++q) {
            rv[q]     = bf2f((unsigned short)r0[q]);
            rv[8 + q] = bf2f((unsigned short)r1[q]);
        }
    }

    float acc[16];
#pragma unroll
    for (int q = 0; q < 16; ++q) acc[q] = 0.f;
    float s_part = 0.f;

    // chunk 0 gather (always issued)
    unsigned o0 = (unsigned)(adjs[half][e < nj ? e : 0] * HID) + cb;
    short8 xa0 = *(const short8*)&xlb[o0];
    short8 xb0 = *(const short8*)&xlb[o0 + 8];

    if (nj > SLOTS) {
        int j1 = SLOTS + e;
        unsigned o1 = (unsigned)(adjs[half][j1 < nj ? j1 : 0] * HID) + cb;
        short8 xa1 = *(const short8*)&xlb[o1];
        short8 xb1 = *(const short8*)&xlb[o1 + 8];
        PROC(xa0, xb0, true);            // nj>16 -> all 16 slots of chunk 0 live
        PROC(xa1, xb1, j1 < nj);
        for (int ch = 2; (ch << 4) < nj; ++ch) {   // rare: nj > 32 (~0.04%)
            int j = (ch << 4) + e;
            unsigned oj = (unsigned)(adjs[half][j < nj ? j : 0] * HID) + cb;
            short8 xaj = *(const short8*)&xlb[oj];
            short8 xbj = *(const short8*)&xlb[oj + 8];
            PROC(xaj, xbj, j < nj);
        }
    } else {
        PROC(xa0, xb0, e < nj);
    }

    // swizzled-column float4 store: content quad q of head hh at physical quad
    // 4*hh + ((q+(hh>>1))&3) -> 8 lanes per 16B bank-group, conflict-free
#pragma unroll
    for (int q = 0; q < 4; ++q) {
        int cq = 4 * hh + ((q + (hh >> 1)) & 3);
        float4 v; v.x = acc[q*4]; v.y = acc[q*4+1]; v.z = acc[q*4+2]; v.w = acc[q*4+3];
        *(float4*)&lacc[half][e][cq * 4] = v;
    }
    ls[half][e][hh] = s_part;
    __syncthreads();

    // thread tl owns channel tl of node d
    const int hr = tl >> 4, qq = (tl >> 2) & 3, ww = tl & 3;
    const int colmap = hr * 16 + (((qq + (hr >> 1)) & 3) << 2) + ww;
    float asum = 0.f;
#pragma unroll
    for (int jj = 0; jj < SLOTS; ++jj) asum += lacc[half][jj][colmap];
    float ssum = 0.f;
#pragma unroll
    for (int jj = 0; jj < SLOTS; ++jj) ssum += ls[half][jj][hr];

    float outv = asum / ssum + gbias[tl];
    outv = outv > 0.f ? outv : (__expf(outv) - 1.f);   // ELU(alpha=1)
    outv += bf2f(hbin[(unsigned)d * HID + tl]);        // residual (bf16)

    float s1 = outv, s2 = outv * outv;
#pragma unroll
    for (int o = 32; o; o >>= 1) {
        s1 += __shfl_down(s1, o);
        s2 += __shfl_down(s2, o);
    }
    if ((tl & 63) == 0) { tmp[half][tl >> 6] = s1; tmp[half][2 + (tl >> 6)] = s2; }
    __syncthreads();
    float mu  = (tmp[half][0] + tmp[half][1]) * (1.f / HID);
    float var = (tmp[half][2] + tmp[half][3]) * (1.f / HID) - mu * mu;
    float o = (outv - mu) * rsqrtf(var + LN_EPS) * g[tl] + beta[tl];
    if (hout)  hout [(unsigned)d * HID + tl] = o;
    if (hbout) hbout[(unsigned)d * HID + tl] = f2bf(o);
}

extern "C" void kernel_launch(void* const* d_in, const int* in_sizes, int n_in,
                              void* d_out, int out_size, void* d_ws, size_t ws_size,
                              hipStream_t stream) {
    (void)in_sizes; (void)n_in; (void)out_size; (void)ws_size;
    const float* x        = (const float*)d_in[0];
    const int*   ei       = (const int*)  d_in[1];
    const float* W_in     = (const float*)d_in[2];
    const float* b_in     = (const float*)d_in[3];
    const float* ln_g     = (const float*)d_in[4];
    const float* ln_b     = (const float*)d_in[5];
    const float* Wl       = (const float*)d_in[6];
    const float* bl       = (const float*)d_in[7];
    const float* Wr       = (const float*)d_in[8];
    const float* br       = (const float*)d_in[9];
    const float* att      = (const float*)d_in[10];
    const float* gat_bias = (const float*)d_in[11];
    const float* norm_g   = (const float*)d_in[12];
    const float* norm_b   = (const float*)d_in[13];
    float* out_f = (float*)d_out;

    char* w = (char*)d_ws;
    int*   adj = (int*)w;                           w += (size_t)N_NODES * CAP * 4;
    int*   cnt = (int*)w;                           w += (size_t)N_NODES * 4;
    unsigned short* hb  = (unsigned short*)w;       w += (size_t)N_NODES * HID * 2;
    unsigned short* xlb = (unsigned short*)w;       w += (size_t)N_NODES * HID * 2;
    unsigned short* xrb = (unsigned short*)w;       w += (size_t)N_NODES * HID * 2;
    unsigned short* WtI = (unsigned short*)w;       w += (size_t)IN_DIM * HID * 2;
    unsigned short* Wlt = (unsigned short*)w;       w += (size_t)LAYERS * HID * HID * 2;
    unsigned short* Wrt = (unsigned short*)w;

    k_convert<<<512, 256, 0, stream>>>(W_in, Wl, Wr, WtI, Wlt, Wrt, cnt);
    k_fused0<<<PROJ_BLKS + EDGE_BLKS + SELF_BLKS, 128, 0, stream>>>(
        x, WtI, b_in, ln_g, ln_b, hb, ei, cnt, adj);

    for (int L = 0; L < LAYERS; ++L) {
        k_xlxr<<<N_NODES / 32, 256, 0, stream>>>(
            hb, Wlt + (size_t)L * HID * HID, Wrt + (size_t)L * HID * HID,
            bl + (size_t)L * HID, br + (size_t)L * HID, xlb, xrb);
        float*          hout   = (L == LAYERS - 1) ? out_f : (float*)nullptr;
        unsigned short* hbnext = (L == LAYERS - 1) ? (unsigned short*)nullptr : hb;
        k_gat<<<N_NODES / 2, 256, 0, stream>>>(
            xlb, xrb, adj, cnt,
            att + (size_t)L * HEADS * C_DIM, gat_bias + (size_t)L * HID,
            norm_g + (size_t)L * HID, norm_b + (size_t)L * HID, hb, hout, hbnext);
    }
}

// Round 12
// 139.620 us; speedup vs baseline: 1.0349x; 1.0349x over previous
//
#include <hip/hip_runtime.h>
#include <math.h>

#define N_NODES 20000
#define IN_DIM  512
#define HID     128
#define HEADS   8
#define C_DIM   16
#define LAYERS  2
#define NEDGE   320000
#define NEG_SLOPE 0.2f
#define LN_EPS  1e-5f
#define CAP     64   // ELL capacity (incl. self loop); deg ~ Poisson(16)
#define SLOTS   16   // edge slots per k_gat chunk

#define PROJ_BLKS  625                         // N_NODES/32
#define EDGE_BLKS  ((NEDGE + 127) / 128)       // 2500
#define SELF_BLKS  ((N_NODES + 127) / 128)     // 157
#define XCHUNKS    (N_NODES * IN_DIM / 8)      // 1,280,000 short8 groups

typedef __attribute__((ext_vector_type(8))) short short8;
typedef __attribute__((ext_vector_type(4))) float f32x4;

__device__ __forceinline__ unsigned short f2bf(float f) {
    unsigned int u = __float_as_uint(f);
    u += 0x7fffu + ((u >> 16) & 1u);
    return (unsigned short)(u >> 16);
}
__device__ __forceinline__ float bf2f(unsigned short s) {
    return __uint_as_float(((unsigned int)s) << 16);
}

// ------- one-time streaming: cnt=0; weights -> bf16 [n][k]; x -> bf16 -------
__global__ __launch_bounds__(256) void k_convert(
    const float* __restrict__ W_in, const float* __restrict__ Wl, const float* __restrict__ Wr,
    const float* __restrict__ x,
    unsigned short* __restrict__ WtI, unsigned short* __restrict__ Wlt, unsigned short* __restrict__ Wrt,
    unsigned short* __restrict__ xb, int* __restrict__ cnt)
{
    int i = blockIdx.x * 256 + threadIdx.x;
    if (i < XCHUNKS) {                    // x -> bf16, 8 elems/thread, coalesced
        const float4* ps = (const float4*)&x[(size_t)i * 8];
        float4 va = ps[0], vb = ps[1];
        short8 o;
        o[0] = (short)f2bf(va.x); o[1] = (short)f2bf(va.y);
        o[2] = (short)f2bf(va.z); o[3] = (short)f2bf(va.w);
        o[4] = (short)f2bf(vb.x); o[5] = (short)f2bf(vb.y);
        o[6] = (short)f2bf(vb.z); o[7] = (short)f2bf(vb.w);
        *(short8*)&xb[(size_t)i * 8] = o;
    }
    if (i < N_NODES) cnt[i] = 0;
    if (i < 65536) {                      // read W_in[k][n] coalesced, write WtI[n][k]
        int n = i & 127, k = i >> 7;
        WtI[(unsigned)n * IN_DIM + k] = f2bf(W_in[(unsigned)k * HID + n]);
    } else if (i < 98304) {               // Wlt[L][n][k]
        int r = i - 65536;
        int L = r >> 14, q = r & 16383;
        int n = q & 127, k = q >> 7;
        Wlt[L * 16384 + n * HID + k] = f2bf(Wl[L * 16384 + k * HID + n]);
    } else if (i < 131072) {              // Wrt[L][n][k]
        int r = i - 98304;
        int L = r >> 14, q = r & 16383;
        int n = q & 127, k = q >> 7;
        Wrt[L * 16384 + n * HID + k] = f2bf(Wr[L * 16384 + k * HID + n]);
    }
}

// ------- fused: input proj (blocks [0,625)) + edge build + self-loop insert -------
// proj: A-fragments direct from bf16 xb (16 independent loads/lane, no LDS/barrier);
// B-fragments from L2-hot WtI (128 KB shared by all blocks).
__global__ __launch_bounds__(128) void k_fused0(
    const unsigned short* __restrict__ xb, const unsigned short* __restrict__ WtI,
    const float* __restrict__ b, const float* __restrict__ g, const float* __restrict__ beta,
    unsigned short* __restrict__ hb,
    const int* __restrict__ ei, int* __restrict__ cnt, int* __restrict__ adj)
{
    const int bid = blockIdx.x;
    const int tid = threadIdx.x;

    if (bid >= PROJ_BLKS) {
        if (bid < PROJ_BLKS + EDGE_BLKS) {
            int e = (bid - PROJ_BLKS) * 128 + tid;
            if (e < NEDGE) {
                int src = ei[e];
                int dst = ei[NEDGE + e];
                int r = atomicAdd(&cnt[dst], 1);
                if (r < CAP) adj[(unsigned)dst * CAP + r] = src;
            }
        } else {
            int i = (bid - PROJ_BLKS - EDGE_BLKS) * 128 + tid;
            if (i < N_NODES) {
                int r = atomicAdd(&cnt[i], 1);
                if (r < CAP) adj[(unsigned)i * CAP + r] = i;
            }
        }
        return;
    }

    const int wid = tid >> 6;
    const int l   = tid & 63;
    const int grp = l >> 4;
    const int ln  = l & 15;
    const int row0 = bid * 32;
    const int arow = row0 + wid * 16 + ln;

    // preload all 16 A-fragments (independent 16B loads -> deep MLP)
    short8 a[16];
#pragma unroll
    for (int ks = 0; ks < 16; ++ks)
        a[ks] = *(const short8*)&xb[(unsigned)arow * IN_DIM + ks * 32 + grp * 8];

    f32x4 acc[8];
#pragma unroll
    for (int j = 0; j < 8; ++j) acc[j] = (f32x4){0.f, 0.f, 0.f, 0.f};
#pragma unroll
    for (int j = 0; j < 8; ++j) {
        const unsigned short* pw = &WtI[(unsigned)(j * 16 + ln) * IN_DIM + grp * 8];
#pragma unroll
        for (int ks = 0; ks < 16; ++ks) {
            short8 bf = *(const short8*)&pw[ks * 32];
            acc[j] = __builtin_amdgcn_mfma_f32_16x16x32_bf16(a[ks], bf, acc[j], 0, 0, 0);
        }
    }

    // epilogue: +bias, LN over 128 cols, ReLU
    float s1[4] = {0, 0, 0, 0}, s2[4] = {0, 0, 0, 0};
#pragma unroll
    for (int j = 0; j < 8; ++j) {
        float bb = b[j * 16 + ln];
#pragma unroll
        for (int r = 0; r < 4; ++r) {
            float v = acc[j][r] + bb;
            acc[j][r] = v;
            s1[r] += v; s2[r] += v * v;
        }
    }
#pragma unroll
    for (int r = 0; r < 4; ++r) {
#pragma unroll
        for (int off = 8; off; off >>= 1) {
            s1[r] += __shfl_xor(s1[r], off);
            s2[r] += __shfl_xor(s2[r], off);
        }
    }
#pragma unroll
    for (int r = 0; r < 4; ++r) {
        float mu  = s1[r] * (1.f / HID);
        float var = s2[r] * (1.f / HID) - mu * mu;
        float rs  = rsqrtf(var + LN_EPS);
        int row = row0 + wid * 16 + grp * 4 + r;
#pragma unroll
        for (int j = 0; j < 8; ++j) {
            int c = j * 16 + ln;
            float o = (acc[j][r] - mu) * rs * g[c] + beta[c];
            hb[(unsigned)row * HID + c] = f2bf(fmaxf(o, 0.f));
        }
    }
}

// ------- per-layer MFMA (R10-proven): LDS-staged weights, 128 threads -------
__global__ __launch_bounds__(128) void k_xlxr(
    const unsigned short* __restrict__ hb,
    const unsigned short* __restrict__ Wlt, const unsigned short* __restrict__ Wrt,
    const float* __restrict__ bl, const float* __restrict__ br,
    unsigned short* __restrict__ xlb, unsigned short* __restrict__ xrb)
{
    __shared__ unsigned short wl_lds[128][136];
    __shared__ unsigned short wr_lds[128][136];
    const int tid = threadIdx.x;
    const int wid = tid >> 6;
    const int l   = tid & 63;
    const int grp = l >> 4;
    const int ln  = l & 15;
    const int row0 = blockIdx.x * 32;
    const int arow = row0 + wid * 16 + ln;

    const int sr = tid >> 4;
    const int sc = (tid & 15) * 8;
#pragma unroll
    for (int rr = sr; rr < 128; rr += 8) {
        *(short8*)&wl_lds[rr][sc] = *(const short8*)&Wlt[rr * HID + sc];
        *(short8*)&wr_lds[rr][sc] = *(const short8*)&Wrt[rr * HID + sc];
    }
    __syncthreads();

    f32x4 aL[8], aR[8];
#pragma unroll
    for (int j = 0; j < 8; ++j) {
        aL[j] = (f32x4){0.f, 0.f, 0.f, 0.f};
        aR[j] = (f32x4){0.f, 0.f, 0.f, 0.f};
    }
#pragma unroll
    for (int ks = 0; ks < 4; ++ks) {
        const int kk = ks * 32 + grp * 8;
        short8 a = *(const short8*)&hb[(unsigned)arow * HID + kk];
#pragma unroll
        for (int j = 0; j < 8; ++j) {
            short8 b8l = *(short8*)&wl_lds[j * 16 + ln][kk];
            aL[j] = __builtin_amdgcn_mfma_f32_16x16x32_bf16(a, b8l, aL[j], 0, 0, 0);
            short8 b8r = *(short8*)&wr_lds[j * 16 + ln][kk];
            aR[j] = __builtin_amdgcn_mfma_f32_16x16x32_bf16(a, b8r, aR[j], 0, 0, 0);
        }
    }
#pragma unroll
    for (int r = 0; r < 4; ++r) {
        int row = row0 + wid * 16 + grp * 4 + r;
#pragma unroll
        for (int j = 0; j < 8; ++j) {
            int c = j * 16 + ln;
            xlb[(unsigned)row * HID + c] = f2bf(aL[j][r] + bl[c]);
            xrb[(unsigned)row * HID + c] = f2bf(aR[j][r] + br[c]);
        }
    }
}

// per-slot work: convert gathered row, logit, exp, accumulate
#define PROC(xa, xb_, live) do {                                            \
    float xf[16];                                                           \
    _Pragma("unroll")                                                       \
    for (int q = 0; q < 8; ++q) {                                           \
        xf[q]     = bf2f((unsigned short)(xa)[q]);                          \
        xf[8 + q] = bf2f((unsigned short)(xb_)[q]);                         \
    }                                                                       \
    float ll = 0.f;                                                         \
    _Pragma("unroll")                                                       \
    for (int q = 0; q < 16; ++q) {                                          \
        float u = xf[q] + rv[q];                                            \
        u = fmaxf(u, NEG_SLOPE * u);                                        \
        ll = fmaf(av[q], u, ll);                                            \
    }                                                                       \
    float p = (live) ? __expf(ll) : 0.f;                                    \
    s_part += p;                                                            \
    _Pragma("unroll")                                                       \
    for (int q = 0; q < 16; ++q) acc[q] = fmaf(p, xf[q], acc[q]);           \
} while (0)

// ------- fused GAT layer (R10-proven): 16 slots x 8 heads, dual-chunk hoist -------
__global__ __launch_bounds__(128) void k_gat(
    const unsigned short* __restrict__ xlb, const unsigned short* __restrict__ xrb,
    const int* __restrict__ adj, const int* __restrict__ cnt,
    const float* __restrict__ att, const float* __restrict__ gbias,
    const float* __restrict__ g, const float* __restrict__ beta,
    const unsigned short* __restrict__ hbin, float* __restrict__ hout,
    unsigned short* __restrict__ hbout)
{
    __shared__ int   adjs[CAP];
    __shared__ float lacc[SLOTS][132];   // row stride 33 float4s (odd) -> bank spread
    __shared__ float ls[SLOTS][HEADS];
    __shared__ float tmp[4];
    const int d  = blockIdx.x;
    const int t  = threadIdx.x;
    const int e  = t >> 3;
    const int hh = t & 7;
    const int cb = hh * 16;

    const int nj = min(cnt[d], CAP);     // includes self loop (atomic insert)
    if (t < nj) adjs[t] = adj[(unsigned)d * CAP + t];
    __syncthreads();

    float av[16], rv[16];
#pragma unroll
    for (int q = 0; q < 4; ++q) {
        float4 a4 = *(const float4*)&att[cb + q * 4];
        av[q*4+0] = a4.x; av[q*4+1] = a4.y; av[q*4+2] = a4.z; av[q*4+3] = a4.w;
    }
    {
        const short8* pr = (const short8*)&xrb[(unsigned)d * HID + cb];
        short8 r0 = pr[0], r1 = pr[1];
#pragma unroll
        for (int q = 0; q < 8; ++q) {
            rv[q]     = bf2f((unsigned short)r0[q]);
            rv[8 + q] = bf2f((unsigned short)r1[q]);
        }
    }

    float acc[16];
#pragma unroll
    for (int q = 0; q < 16; ++q) acc[q] = 0.f;
    float s_part = 0.f;

    // chunk 0 gather (always issued)
    unsigned o0 = (unsigned)(adjs[e < nj ? e : 0] * HID) + cb;
    short8 xa0 = *(const short8*)&xlb[o0];
    short8 xb0 = *(const short8*)&xlb[o0 + 8];

    if (nj > SLOTS) {
        // chunk 1 gather issued BEFORE chunk-0 compute (latency overlap)
        int j1 = SLOTS + e;
        unsigned o1 = (unsigned)(adjs[j1 < nj ? j1 : 0] * HID) + cb;
        short8 xa1 = *(const short8*)&xlb[o1];
        short8 xb1 = *(const short8*)&xlb[o1 + 8];
        PROC(xa0, xb0, true);            // nj>16 -> all 16 slots of chunk 0 live
        PROC(xa1, xb1, j1 < nj);
        for (int ch = 2; (ch << 4) < nj; ++ch) {   // rare: nj > 32 (~0.04%)
            int j = (ch << 4) + e;
            unsigned oj = (unsigned)(adjs[j < nj ? j : 0] * HID) + cb;
            short8 xaj = *(const short8*)&xlb[oj];
            short8 xbj = *(const short8*)&xlb[oj + 8];
            PROC(xaj, xbj, j < nj);
        }
    } else {
        PROC(xa0, xb0, e < nj);
    }

    // swizzled-column float4 store: content quad q of head hh at physical quad
    // 4*hh + ((q+(hh>>1))&3) -> 8 lanes per 16B bank-group, conflict-free
#pragma unroll
    for (int q = 0; q < 4; ++q) {
        int cq = 4 * hh + ((q + (hh >> 1)) & 3);
        float4 v; v.x = acc[q*4]; v.y = acc[q*4+1]; v.z = acc[q*4+2]; v.w = acc[q*4+3];
        *(float4*)&lacc[e][cq * 4] = v;
    }
    ls[e][hh] = s_part;
    __syncthreads();

    // thread t owns channel t
    const int hr = t >> 4, qq = (t >> 2) & 3, ww = t & 3;
    const int colmap = hr * 16 + (((qq + (hr >> 1)) & 3) << 2) + ww;
    float asum = 0.f;
#pragma unroll
    for (int jj = 0; jj < SLOTS; ++jj) asum += lacc[jj][colmap];
    float ssum = 0.f;
#pragma unroll
    for (int jj = 0; jj < SLOTS; ++jj) ssum += ls[jj][hr];

    float outv = asum / ssum + gbias[t];
    outv = outv > 0.f ? outv : (__expf(outv) - 1.f);   // ELU(alpha=1)
    outv += bf2f(hbin[(unsigned)d * HID + t]);         // residual (bf16)

    float s1 = outv, s2 = outv * outv;
#pragma unroll
    for (int o = 32; o; o >>= 1) {
        s1 += __shfl_down(s1, o);
        s2 += __shfl_down(s2, o);
    }
    if ((t & 63) == 0) { tmp[t >> 6] = s1; tmp[2 + (t >> 6)] = s2; }
    __syncthreads();
    float mu  = (tmp[0] + tmp[1]) * (1.f / HID);
    float var = (tmp[2] + tmp[3]) * (1.f / HID) - mu * mu;
    float o = (outv - mu) * rsqrtf(var + LN_EPS) * g[t] + beta[t];
    if (hout)  hout [(unsigned)d * HID + t] = o;
    if (hbout) hbout[(unsigned)d * HID + t] = f2bf(o);
}

extern "C" void kernel_launch(void* const* d_in, const int* in_sizes, int n_in,
                              void* d_out, int out_size, void* d_ws, size_t ws_size,
                              hipStream_t stream) {
    (void)in_sizes; (void)n_in; (void)out_size; (void)ws_size;
    const float* x        = (const float*)d_in[0];
    const int*   ei       = (const int*)  d_in[1];
    const float* W_in     = (const float*)d_in[2];
    const float* b_in     = (const float*)d_in[3];
    const float* ln_g     = (const float*)d_in[4];
    const float* ln_b     = (const float*)d_in[5];
    const float* Wl       = (const float*)d_in[6];
    const float* bl       = (const float*)d_in[7];
    const float* Wr       = (const float*)d_in[8];
    const float* br       = (const float*)d_in[9];
    const float* att      = (const float*)d_in[10];
    const float* gat_bias = (const float*)d_in[11];
    const float* norm_g   = (const float*)d_in[12];
    const float* norm_b   = (const float*)d_in[13];
    float* out_f = (float*)d_out;

    char* w = (char*)d_ws;
    int*   adj = (int*)w;                           w += (size_t)N_NODES * CAP * 4;
    int*   cnt = (int*)w;                           w += (size_t)N_NODES * 4;
    unsigned short* xb  = (unsigned short*)w;       w += (size_t)N_NODES * IN_DIM * 2;  // 20.5 MB
    unsigned short* hb  = (unsigned short*)w;       w += (size_t)N_NODES * HID * 2;
    unsigned short* xlb = (unsigned short*)w;       w += (size_t)N_NODES * HID * 2;
    unsigned short* xrb = (unsigned short*)w;       w += (size_t)N_NODES * HID * 2;
    unsigned short* WtI = (unsigned short*)w;       w += (size_t)IN_DIM * HID * 2;
    unsigned short* Wlt = (unsigned short*)w;       w += (size_t)LAYERS * HID * HID * 2;
    unsigned short* Wrt = (unsigned short*)w;

    k_convert<<<(XCHUNKS + 255) / 256, 256, 0, stream>>>(
        W_in, Wl, Wr, x, WtI, Wlt, Wrt, xb, cnt);
    k_fused0<<<PROJ_BLKS + EDGE_BLKS + SELF_BLKS, 128, 0, stream>>>(
        xb, WtI, b_in, ln_g, ln_b, hb, ei, cnt, adj);

    for (int L = 0; L < LAYERS; ++L) {
        k_xlxr<<<N_NODES / 32, 128, 0, stream>>>(
            hb, Wlt + (size_t)L * HID * HID, Wrt + (size_t)L * HID * HID,
            bl + (size_t)L * HID, br + (size_t)L * HID, xlb, xrb);
        float*          hout   = (L == LAYERS - 1) ? out_f : (float*)nullptr;
        unsigned short* hbnext = (L == LAYERS - 1) ? (unsigned short*)nullptr : hb;
        k_gat<<<N_NODES, 128, 0, stream>>>(
            xlb, xrb, adj, cnt,
            att + (size_t)L * HEADS * C_DIM, gat_bias + (size_t)L * HID,
            norm_g + (size_t)L * HID, norm_b + (size_t)L * HID, hb, hout, hbnext);
    }
}

// Round 13
// 123.469 us; speedup vs baseline: 1.1703x; 1.1308x over previous
//
#include <hip/hip_runtime.h>
#include <math.h>

#define N_NODES 20000
#define IN_DIM  512
#define HID     128
#define HEADS   8
#define C_DIM   16
#define LAYERS  2
#define NEDGE   320000
#define NEG_SLOPE 0.2f
#define LN_EPS  1e-5f
#define CAP     64   // ELL capacity (incl. self loop); deg ~ Poisson(16)

#define PROJ_BLKS  625                         // N_NODES/32
#define EDGE_BLKS  ((NEDGE + 127) / 128)       // 2500
#define SELF_BLKS  ((N_NODES + 127) / 128)     // 157

typedef __attribute__((ext_vector_type(8))) short short8;
typedef __attribute__((ext_vector_type(4))) float f32x4;

__device__ __forceinline__ unsigned short f2bf(float f) {
    unsigned int u = __float_as_uint(f);
    u += 0x7fffu + ((u >> 16) & 1u);
    return (unsigned short)(u >> 16);
}
__device__ __forceinline__ float bf2f(unsigned short s) {
    return __uint_as_float(((unsigned int)s) << 16);
}

// ------- one-time: cnt=0; weights -> bf16 transposed [n][k] (coalesced reads) -------
__global__ __launch_bounds__(256) void k_convert(
    const float* __restrict__ W_in, const float* __restrict__ Wl, const float* __restrict__ Wr,
    unsigned short* __restrict__ WtI, unsigned short* __restrict__ Wlt, unsigned short* __restrict__ Wrt,
    int* __restrict__ cnt)
{
    int i = blockIdx.x * 256 + threadIdx.x;
    if (i < N_NODES) cnt[i] = 0;
    if (i < 65536) {                      // read W_in[k][n] coalesced, write WtI[n][k]
        int n = i & 127, k = i >> 7;
        WtI[(unsigned)n * IN_DIM + k] = f2bf(W_in[(unsigned)k * HID + n]);
    } else if (i < 98304) {               // Wlt[L][n][k]
        int r = i - 65536;
        int L = r >> 14, q = r & 16383;
        int n = q & 127, k = q >> 7;
        Wlt[L * 16384 + n * HID + k] = f2bf(Wl[L * 16384 + k * HID + n]);
    } else if (i < 131072) {              // Wrt[L][n][k]
        int r = i - 98304;
        int L = r >> 14, q = r & 16383;
        int n = q & 127, k = q >> 7;
        Wrt[L * 16384 + n * HID + k] = f2bf(Wr[L * 16384 + k * HID + n]);
    }
}

// ------- fused: input proj (blocks [0,625)) + edge build + self-loop insert -------
// (R10-proven form: x + weights staged through LDS)
__global__ __launch_bounds__(128) void k_fused0(
    const float* __restrict__ x, const unsigned short* __restrict__ WtI,
    const float* __restrict__ b, const float* __restrict__ g, const float* __restrict__ beta,
    unsigned short* __restrict__ hb,
    const int* __restrict__ ei, int* __restrict__ cnt, int* __restrict__ adj)
{
    __shared__ unsigned short wlds[128][136];   // [n][k-chunk]
    __shared__ unsigned short xtile[32][136];   // [row][k-chunk] bf16
    const int bid = blockIdx.x;
    const int tid = threadIdx.x;

    if (bid >= PROJ_BLKS) {
        if (bid < PROJ_BLKS + EDGE_BLKS) {
            int e = (bid - PROJ_BLKS) * 128 + tid;
            if (e < NEDGE) {
                int src = ei[e];
                int dst = ei[NEDGE + e];
                int r = atomicAdd(&cnt[dst], 1);
                if (r < CAP) adj[(unsigned)dst * CAP + r] = src;
            }
        } else {
            int i = (bid - PROJ_BLKS - EDGE_BLKS) * 128 + tid;
            if (i < N_NODES) {
                int r = atomicAdd(&cnt[i], 1);
                if (r < CAP) adj[(unsigned)i * CAP + r] = i;
            }
        }
        return;
    }

    const int wid = tid >> 6;
    const int l   = tid & 63;
    const int grp = l >> 4;
    const int ln  = l & 15;
    const int row0 = bid * 32;

    f32x4 acc[8];
#pragma unroll
    for (int j = 0; j < 8; ++j) acc[j] = (f32x4){0.f, 0.f, 0.f, 0.f};

    const int sr = tid >> 4;
    const int sc = (tid & 15) * 8;
    const int xrr = tid >> 2;            // x staging: row
    const int xcc = (tid & 3) * 32;      // x staging: col base

    for (int kc = 0; kc < 4; ++kc) {
        __syncthreads();
#pragma unroll
        for (int rr = sr; rr < 128; rr += 8)
            *(short8*)&wlds[rr][sc] = *(const short8*)&WtI[rr * IN_DIM + kc * 128 + sc];
        {
            const float4* ps = (const float4*)&x[(unsigned)(row0 + xrr) * IN_DIM + kc * 128 + xcc];
#pragma unroll
            for (int q = 0; q < 4; ++q) {
                float4 va = ps[2 * q], vb = ps[2 * q + 1];
                short8 o;
                o[0] = (short)f2bf(va.x); o[1] = (short)f2bf(va.y);
                o[2] = (short)f2bf(va.z); o[3] = (short)f2bf(va.w);
                o[4] = (short)f2bf(vb.x); o[5] = (short)f2bf(vb.y);
                o[6] = (short)f2bf(vb.z); o[7] = (short)f2bf(vb.w);
                *(short8*)&xtile[xrr][xcc + q * 8] = o;
            }
        }
        __syncthreads();
#pragma unroll
        for (int ks = 0; ks < 4; ++ks) {
            short8 a = *(short8*)&xtile[wid * 16 + ln][ks * 32 + grp * 8];
#pragma unroll
            for (int j = 0; j < 8; ++j) {
                short8 bf = *(short8*)&wlds[j * 16 + ln][ks * 32 + grp * 8];
                acc[j] = __builtin_amdgcn_mfma_f32_16x16x32_bf16(a, bf, acc[j], 0, 0, 0);
            }
        }
    }
    // epilogue: +bias, LN over 128 cols, ReLU
    float s1[4] = {0, 0, 0, 0}, s2[4] = {0, 0, 0, 0};
#pragma unroll
    for (int j = 0; j < 8; ++j) {
        float bb = b[j * 16 + ln];
#pragma unroll
        for (int r = 0; r < 4; ++r) {
            float v = acc[j][r] + bb;
            acc[j][r] = v;
            s1[r] += v; s2[r] += v * v;
        }
    }
#pragma unroll
    for (int r = 0; r < 4; ++r) {
#pragma unroll
        for (int off = 8; off; off >>= 1) {
            s1[r] += __shfl_xor(s1[r], off);
            s2[r] += __shfl_xor(s2[r], off);
        }
    }
#pragma unroll
    for (int r = 0; r < 4; ++r) {
        float mu  = s1[r] * (1.f / HID);
        float var = s2[r] * (1.f / HID) - mu * mu;
        float rs  = rsqrtf(var + LN_EPS);
        int row = row0 + wid * 16 + grp * 4 + r;
#pragma unroll
        for (int j = 0; j < 8; ++j) {
            int c = j * 16 + ln;
            float o = (acc[j][r] - mu) * rs * g[c] + beta[c];
            hb[(unsigned)row * HID + c] = f2bf(fmaxf(o, 0.f));
        }
    }
}

// ------- per-layer MFMA (R10-proven): LDS-staged weights, 128 threads -------
__global__ __launch_bounds__(128) void k_xlxr(
    const unsigned short* __restrict__ hb,
    const unsigned short* __restrict__ Wlt, const unsigned short* __restrict__ Wrt,
    const float* __restrict__ bl, const float* __restrict__ br,
    unsigned short* __restrict__ xlb, unsigned short* __restrict__ xrb)
{
    __shared__ unsigned short wl_lds[128][136];
    __shared__ unsigned short wr_lds[128][136];
    const int tid = threadIdx.x;
    const int wid = tid >> 6;
    const int l   = tid & 63;
    const int grp = l >> 4;
    const int ln  = l & 15;
    const int row0 = blockIdx.x * 32;
    const int arow = row0 + wid * 16 + ln;

    const int sr = tid >> 4;
    const int sc = (tid & 15) * 8;
#pragma unroll
    for (int rr = sr; rr < 128; rr += 8) {
        *(short8*)&wl_lds[rr][sc] = *(const short8*)&Wlt[rr * HID + sc];
        *(short8*)&wr_lds[rr][sc] = *(const short8*)&Wrt[rr * HID + sc];
    }
    __syncthreads();

    f32x4 aL[8], aR[8];
#pragma unroll
    for (int j = 0; j < 8; ++j) {
        aL[j] = (f32x4){0.f, 0.f, 0.f, 0.f};
        aR[j] = (f32x4){0.f, 0.f, 0.f, 0.f};
    }
#pragma unroll
    for (int ks = 0; ks < 4; ++ks) {
        const int kk = ks * 32 + grp * 8;
        short8 a = *(const short8*)&hb[(unsigned)arow * HID + kk];
#pragma unroll
        for (int j = 0; j < 8; ++j) {
            short8 b8l = *(short8*)&wl_lds[j * 16 + ln][kk];
            aL[j] = __builtin_amdgcn_mfma_f32_16x16x32_bf16(a, b8l, aL[j], 0, 0, 0);
            short8 b8r = *(short8*)&wr_lds[j * 16 + ln][kk];
            aR[j] = __builtin_amdgcn_mfma_f32_16x16x32_bf16(a, b8r, aR[j], 0, 0, 0);
        }
    }
#pragma unroll
    for (int r = 0; r < 4; ++r) {
        int row = row0 + wid * 16 + grp * 4 + r;
#pragma unroll
        for (int j = 0; j < 8; ++j) {
            int c = j * 16 + ln;
            xlb[(unsigned)row * HID + c] = f2bf(aL[j][r] + bl[c]);
            xrb[(unsigned)row * HID + c] = f2bf(aR[j][r] + br[c]);
        }
    }
}

// per-slot work: convert gathered row, logit, exp, accumulate
#define PROC(xa, xb_, live) do {                                            \
    float xf[16];                                                           \
    _Pragma("unroll")                                                       \
    for (int q = 0; q < 8; ++q) {                                           \
        xf[q]     = bf2f((unsigned short)(xa)[q]);                          \
        xf[8 + q] = bf2f((unsigned short)(xb_)[q]);                         \
    }                                                                       \
    float ll = 0.f;                                                         \
    _Pragma("unroll")                                                       \
    for (int q = 0; q < 16; ++q) {                                          \
        float u = xf[q] + rv[q];                                            \
        u = fmaxf(u, NEG_SLOPE * u);                                        \
        ll = fmaf(av[q], u, ll);                                            \
    }                                                                       \
    float p = (live) ? __expf(ll) : 0.f;                                    \
    sp += p;                                                                \
    _Pragma("unroll")                                                       \
    for (int q = 0; q < 16; ++q) acc[q] = fmaf(p, xf[q], acc[q]);           \
} while (0)

// ------- fused GAT layer: ONE WAVE PER NODE, zero barriers -------
// 256-thr block = 4 independent waves; lane = (e=lane>>3 slot, hh=lane&7 head).
// 8-slot chunks: 0,1 always gathered, 2 when nj>16, rare tail loop nj>24.
// Cross-slot reduce: shfl_xor butterfly over e-bits; LDS redistribute is
// wave-private (compiler-inserted lgkmcnt, no __syncthreads anywhere).
__global__ __launch_bounds__(256) void k_gat(
    const unsigned short* __restrict__ xlb, const unsigned short* __restrict__ xrb,
    const int* __restrict__ adj, const int* __restrict__ cnt,
    const float* __restrict__ att, const float* __restrict__ gbias,
    const float* __restrict__ g, const float* __restrict__ beta,
    const unsigned short* __restrict__ hbin, float* __restrict__ hout,
    unsigned short* __restrict__ hbout)
{
    __shared__ float red[4][136];        // per-wave: [0..127] acc, [128..135] head sums
    const int tid  = threadIdx.x;
    const int wv   = tid >> 6;
    const int lane = tid & 63;
    const int d    = blockIdx.x * 4 + wv;
    const int e    = lane >> 3;
    const int hh   = lane & 7;
    const int cb   = hh * 16;
    const unsigned dC = (unsigned)d * CAP;

    // independent loads issued up front
    const int nj = min(cnt[d], CAP);     // includes self loop (atomic insert)
    int aj0 = adj[dC + e];               // slots 0..7   (always within row)
    int aj1 = adj[dC + 8 + e];           // slots 8..15
    int aj2 = adj[dC + 16 + e];          // slots 16..23

    float av[16], rv[16];
#pragma unroll
    for (int q = 0; q < 4; ++q) {
        float4 a4 = *(const float4*)&att[cb + q * 4];
        av[q*4+0] = a4.x; av[q*4+1] = a4.y; av[q*4+2] = a4.z; av[q*4+3] = a4.w;
    }
    {
        const short8* pr = (const short8*)&xrb[(unsigned)d * HID + cb];
        short8 r0 = pr[0], r1 = pr[1];
#pragma unroll
        for (int q = 0; q < 8; ++q) {
            rv[q]     = bf2f((unsigned short)r0[q]);
            rv[8 + q] = bf2f((unsigned short)r1[q]);
        }
    }

    // clamp dead slots to self row d (always valid), then issue gathers
    const int src0 = (e < nj)      ? aj0 : d;
    const int src1 = (8 + e < nj)  ? aj1 : d;
    const int src2 = (16 + e < nj) ? aj2 : d;
    const short8* p0 = (const short8*)&xlb[(unsigned)src0 * HID + cb];
    short8 ga0 = p0[0], gb0 = p0[1];
    const short8* p1 = (const short8*)&xlb[(unsigned)src1 * HID + cb];
    short8 ga1 = p1[0], gb1 = p1[1];

    float acc[16];
#pragma unroll
    for (int q = 0; q < 16; ++q) acc[q] = 0.f;
    float sp = 0.f;

    if (nj > 16) {                       // wave-uniform branch (~53%)
        const short8* p2 = (const short8*)&xlb[(unsigned)src2 * HID + cb];
        short8 ga2 = p2[0], gb2 = p2[1];
        PROC(ga0, gb0, e < nj);
        PROC(ga1, gb1, true);            // nj>16 -> all of chunk 1 live
        PROC(ga2, gb2, 16 + e < nj);
        for (int ch = 3; (ch << 3) < nj; ++ch) {   // rare: nj > 24 (~3.4%)
            int j = (ch << 3) + e;
            int ajv = adj[dC + (j < nj ? j : 0)];
            int sj  = (j < nj) ? ajv : d;
            const short8* pj = (const short8*)&xlb[(unsigned)sj * HID + cb];
            short8 gaj = pj[0], gbj = pj[1];
            PROC(gaj, gbj, j < nj);
        }
    } else {
        PROC(ga0, gb0, e < nj);
        PROC(ga1, gb1, 8 + e < nj);
    }

    // butterfly reduce across the 8 slot-lanes (e-bits are lane bits 3..5)
#pragma unroll
    for (int m = 8; m < 64; m <<= 1) {
#pragma unroll
        for (int q = 0; q < 16; ++q) acc[q] += __shfl_xor(acc[q], m);
        sp += __shfl_xor(sp, m);
    }

    // wave-private LDS redistribute (no barrier: same-wave LDS dependency)
    if (lane < 8) {                      // lane == hh, e == 0
#pragma unroll
        for (int q = 0; q < 16; q += 4) {
            float4 v; v.x = acc[q]; v.y = acc[q+1]; v.z = acc[q+2]; v.w = acc[q+3];
            *(float4*)&red[wv][lane * 16 + q] = v;
        }
        red[wv][128 + lane] = sp;
    }
    const int c0 = lane * 2;
    float a0  = red[wv][c0];
    float a1  = red[wv][c0 + 1];
    float ssv = red[wv][128 + e];        // head of channel c0 is c0>>4 == e

    float2 gbv = *(const float2*)&gbias[c0];
    float2 ggv = *(const float2*)&g[c0];
    float2 bev = *(const float2*)&beta[c0];
    unsigned hr2 = *(const unsigned*)&hbin[(unsigned)d * HID + c0];

    float o0 = a0 / ssv + gbv.x;
    float o1 = a1 / ssv + gbv.y;
    o0 = o0 > 0.f ? o0 : (__expf(o0) - 1.f);   // ELU(alpha=1)
    o1 = o1 > 0.f ? o1 : (__expf(o1) - 1.f);
    o0 += bf2f((unsigned short)(hr2 & 0xffffu));
    o1 += bf2f((unsigned short)(hr2 >> 16));

    float s1l = o0 + o1, s2l = o0 * o0 + o1 * o1;
#pragma unroll
    for (int m = 1; m < 64; m <<= 1) {
        s1l += __shfl_xor(s1l, m);
        s2l += __shfl_xor(s2l, m);
    }
    float mu  = s1l * (1.f / HID);
    float var = s2l * (1.f / HID) - mu * mu;
    float rs  = rsqrtf(var + LN_EPS);
    float out0 = (o0 - mu) * rs * ggv.x + bev.x;
    float out1 = (o1 - mu) * rs * ggv.y + bev.y;
    if (hout) {
        float2 ov; ov.x = out0; ov.y = out1;
        *(float2*)&hout[(unsigned)d * HID + c0] = ov;
    }
    if (hbout) {
        unsigned pk = (unsigned)f2bf(out0) | ((unsigned)f2bf(out1) << 16);
        *(unsigned*)&hbout[(unsigned)d * HID + c0] = pk;
    }
}

extern "C" void kernel_launch(void* const* d_in, const int* in_sizes, int n_in,
                              void* d_out, int out_size, void* d_ws, size_t ws_size,
                              hipStream_t stream) {
    (void)in_sizes; (void)n_in; (void)out_size; (void)ws_size;
    const float* x        = (const float*)d_in[0];
    const int*   ei       = (const int*)  d_in[1];
    const float* W_in     = (const float*)d_in[2];
    const float* b_in     = (const float*)d_in[3];
    const float* ln_g     = (const float*)d_in[4];
    const float* ln_b     = (const float*)d_in[5];
    const float* Wl       = (const float*)d_in[6];
    const float* bl       = (const float*)d_in[7];
    const float* Wr       = (const float*)d_in[8];
    const float* br       = (const float*)d_in[9];
    const float* att      = (const float*)d_in[10];
    const float* gat_bias = (const float*)d_in[11];
    const float* norm_g   = (const float*)d_in[12];
    const float* norm_b   = (const float*)d_in[13];
    float* out_f = (float*)d_out;

    char* w = (char*)d_ws;
    int*   adj = (int*)w;                           w += (size_t)N_NODES * CAP * 4;
    int*   cnt = (int*)w;                           w += (size_t)N_NODES * 4;
    unsigned short* hb  = (unsigned short*)w;       w += (size_t)N_NODES * HID * 2;
    unsigned short* xlb = (unsigned short*)w;       w += (size_t)N_NODES * HID * 2;
    unsigned short* xrb = (unsigned short*)w;       w += (size_t)N_NODES * HID * 2;
    unsigned short* WtI = (unsigned short*)w;       w += (size_t)IN_DIM * HID * 2;
    unsigned short* Wlt = (unsigned short*)w;       w += (size_t)LAYERS * HID * HID * 2;
    unsigned short* Wrt = (unsigned short*)w;

    k_convert<<<512, 256, 0, stream>>>(W_in, Wl, Wr, WtI, Wlt, Wrt, cnt);
    k_fused0<<<PROJ_BLKS + EDGE_BLKS + SELF_BLKS, 128, 0, stream>>>(
        x, WtI, b_in, ln_g, ln_b, hb, ei, cnt, adj);

    for (int L = 0; L < LAYERS; ++L) {
        k_xlxr<<<N_NODES / 32, 128, 0, stream>>>(
            hb, Wlt + (size_t)L * HID * HID, Wrt + (size_t)L * HID * HID,
            bl + (size_t)L * HID, br + (size_t)L * HID, xlb, xrb);
        float*          hout   = (L == LAYERS - 1) ? out_f : (float*)nullptr;
        unsigned short* hbnext = (L == LAYERS - 1) ? (unsigned short*)nullptr : hb;
        k_gat<<<N_NODES / 4, 256, 0, stream>>>(
            xlb, xrb, adj, cnt,
            att + (size_t)L * HEADS * C_DIM, gat_bias + (size_t)L * HID,
            norm_g + (size_t)L * HID, norm_b + (size_t)L * HID, hb, hout, hbnext);
    }
}